// Round 2
// baseline (415.024 us; speedup 1.0000x reference)
//
#include <hip/hip_runtime.h>

#define HID 10
#define TT  2048
#define BB  4096

__device__ __forceinline__ float fast_tanh(float x) {
    // tanh(x) = 1 - 2/(exp2(x * 2*log2(e)) + 1); saturates correctly at +-inf
    float e = exp2f(x * 2.885390081777926814f);
    float r = __builtin_amdgcn_rcpf(e + 1.0f);
    return fmaf(-2.0f, r, 1.0f);
}

// DPP row-rotate within each 16-lane row. Direction convention handled by
// self-calibration at weight-load time, so only consistency matters.
template<int CTRL>
__device__ __forceinline__ int rori(int v) {
    return __builtin_amdgcn_update_dpp(0, v, CTRL, 0xF, 0xF, true);
}
template<int CTRL>
__device__ __forceinline__ float rorf(float v) {
    return __int_as_float(
        __builtin_amdgcn_update_dpp(0, __float_as_int(v), CTRL, 0xF, 0xF, true));
}

// 16-term systolic matvec: acc chains a,b,c,d (depth 4 each), w[] pre-rotated.
#define MV16(w, v, a, b, c, d)                          \
    a = fmaf(w[0],  (v),            a);                 \
    a = fmaf(w[1],  rorf<0x121>(v), a);                 \
    a = fmaf(w[2],  rorf<0x122>(v), a);                 \
    a = fmaf(w[3],  rorf<0x123>(v), a);                 \
    b = fmaf(w[4],  rorf<0x124>(v), b);                 \
    b = fmaf(w[5],  rorf<0x125>(v), b);                 \
    b = fmaf(w[6],  rorf<0x126>(v), b);                 \
    b = fmaf(w[7],  rorf<0x127>(v), b);                 \
    c = fmaf(w[8],  rorf<0x128>(v), c);                 \
    c = fmaf(w[9],  rorf<0x129>(v), c);                 \
    c = fmaf(w[10], rorf<0x12A>(v), c);                 \
    c = fmaf(w[11], rorf<0x12B>(v), c);                 \
    d = fmaf(w[12], rorf<0x12C>(v), d);                 \
    d = fmaf(w[13], rorf<0x12D>(v), d);                 \
    d = fmaf(w[14], rorf<0x12E>(v), d);                 \
    d = fmaf(w[15], rorf<0x12F>(v), d);

// lane (0..15) = hidden-unit slot (10 active), 4 rows/wave, 1024 waves.
// All cross-lane traffic via DPP row_ror (VALU pipe) -- zero LDS, zero barriers.
__global__ void __launch_bounds__(64) rnn_kernel(
    const float* __restrict__ x,    const float* __restrict__ hs,
    const float* __restrict__ Wih0, const float* __restrict__ Whh0,
    const float* __restrict__ bih0, const float* __restrict__ bhh0,
    const float* __restrict__ Wih1, const float* __restrict__ Whh1,
    const float* __restrict__ bih1, const float* __restrict__ bhh1,
    const float* __restrict__ Wout, const float* __restrict__ boutp,
    float* __restrict__ out)
{
    const int tid  = threadIdx.x;
    const int lane = tid & 15;          // hidden unit slot
    const int grp  = tid >> 4;          // row within wave
    const int row  = blockIdx.x * 4 + grp;

    // ---- self-calibrate rotation source lanes: jj[r] = unit delivered by ror_r
    int jj[16];
    jj[0]  = lane;
    jj[1]  = rori<0x121>(lane);  jj[2]  = rori<0x122>(lane);
    jj[3]  = rori<0x123>(lane);  jj[4]  = rori<0x124>(lane);
    jj[5]  = rori<0x125>(lane);  jj[6]  = rori<0x126>(lane);
    jj[7]  = rori<0x127>(lane);  jj[8]  = rori<0x128>(lane);
    jj[9]  = rori<0x129>(lane);  jj[10] = rori<0x12A>(lane);
    jj[11] = rori<0x12B>(lane);  jj[12] = rori<0x12C>(lane);
    jj[13] = rori<0x12D>(lane);  jj[14] = rori<0x12E>(lane);
    jj[15] = rori<0x12F>(lane);

    // ---- pre-rotated weight rows (0 for dummy units / dummy sources) ----
    float whh0r[16], wih1r[16], whh1r[16];
    #pragma unroll
    for (int r = 0; r < 16; ++r) {
        const int j = jj[r];
        const bool ok = (lane < HID) && (j < HID);
        whh0r[r] = ok ? Whh0[lane * HID + j] : 0.f;
        wih1r[r] = ok ? Wih1[lane * HID + j] : 0.f;
        whh1r[r] = ok ? Whh1[lane * HID + j] : 0.f;
    }
    const bool act = (lane < HID);
    const float wih0i = act ? Wih0[lane] : 0.f;
    const float b0c   = act ? (bih0[lane] + bhh0[lane]) : 0.f;
    const float b1c   = act ? (bih1[lane] + bhh1[lane]) : 0.f;
    const float woutu = act ? Wout[lane] : 0.f;
    const float bo    = boutp[0];

    // ---- lane-resident state: this lane's unit only ----
    float h0 = act ? hs[row * HID + lane] : 0.f;
    float h1 = act ? hs[BB * HID + row * HID + lane] : 0.f;

    const float* xrow = x   + (size_t)row * TT;
    float*       orow = out + (size_t)row * TT;

    float4 xa = *(const float4*)(xrow);
    float4 xb = *(const float4*)(xrow + 4);

    for (int t0 = 0; t0 < TT; t0 += 8) {
        int tp = t0 + 8; tp = (tp > TT - 8) ? (TT - 8) : tp;
        float4 xc = *(const float4*)(xrow + tp);
        float4 xd = *(const float4*)(xrow + tp + 4);

        float xw[8] = {xa.x, xa.y, xa.z, xa.w, xb.x, xb.y, xb.z, xb.w};
        float o[8];

        #pragma unroll
        for (int k = 0; k < 8; ++k) {
            // ---------- layer 0: h0n = tanh(x*wih0 + Whh0 . h0 + b0) ----------
            float a0 = fmaf(xw[k], wih0i, b0c), b0 = 0.f, c0 = 0.f, d0 = 0.f;
            MV16(whh0r, h0, a0, b0, c0, d0);
            const float h0n = fast_tanh((a0 + b0) + (c0 + d0));

            // ---------- layer 1: h1n = tanh(Wih1 . h0n + Whh1 . h1 + b1) ------
            float a1 = b1c, b1 = 0.f, c1 = 0.f, d1 = 0.f;
            MV16(wih1r, h0n, a1, b1, c1, d1);
            MV16(whh1r, h1,  a1, b1, c1, d1);
            const float h1n = fast_tanh((a1 + b1) + (c1 + d1));

            h0 = h0n;
            h1 = h1n;

            // ---------- out = Wout . h1n + bo : ror-butterfly all-reduce ------
            float p = woutu * h1n;
            p += rorf<0x128>(p);
            p += rorf<0x124>(p);
            p += rorf<0x122>(p);
            p += rorf<0x121>(p);
            o[k] = p + bo;
        }

        if (lane == 0) {
            *(float4*)(orow + t0)     = make_float4(o[0], o[1], o[2], o[3]);
            *(float4*)(orow + t0 + 4) = make_float4(o[4], o[5], o[6], o[7]);
        }
        xa = xc; xb = xd;
    }

    // final hidden state: [2, B, H] appended after the B*T outputs
    if (act) {
        out[(size_t)BB * TT + (size_t)row * HID + lane]                    = h0;
        out[(size_t)BB * TT + (size_t)BB * HID + (size_t)row * HID + lane] = h1;
    }
}

extern "C" void kernel_launch(void* const* d_in, const int* in_sizes, int n_in,
                              void* d_out, int out_size, void* d_ws, size_t ws_size,
                              hipStream_t stream) {
    const float* x    = (const float*)d_in[0];
    const float* hs   = (const float*)d_in[1];
    const float* Wih0 = (const float*)d_in[2];
    const float* Whh0 = (const float*)d_in[3];
    const float* bih0 = (const float*)d_in[4];
    const float* bhh0 = (const float*)d_in[5];
    const float* Wih1 = (const float*)d_in[6];
    const float* Whh1 = (const float*)d_in[7];
    const float* bih1 = (const float*)d_in[8];
    const float* bhh1 = (const float*)d_in[9];
    const float* Wout = (const float*)d_in[10];
    const float* bout = (const float*)d_in[11];
    float* out = (float*)d_out;

    dim3 grid(BB / 4), block(64);
    hipLaunchKernelGGL(rnn_kernel, grid, block, 0, stream,
        x, hs, Wih0, Whh0, bih0, bhh0, Wih1, Whh1, bih1, bhh1, Wout, bout, out);
}

// Round 3
// 413.196 us; speedup vs baseline: 1.0044x; 1.0044x over previous
//
#include <hip/hip_runtime.h>

#define HID 10
#define TT  2048
#define BB  4096

__device__ __forceinline__ float fast_tanh(float x) {
    // tanh(x) = 1 - 2/(exp2(x*2*log2e) + 1); saturates correctly at +-inf
    float e = exp2f(x * 2.885390081777926814f);
    float r = __builtin_amdgcn_rcpf(e + 1.0f);
    return fmaf(-2.0f, r, 1.0f);
}

// 16 lanes per row (lane = hidden unit slot), 4 rows/wave, 1024 waves.
// Software-pipelined: iter i computes layer0(i), layer1(i-1), out(i-2).
// Every LDS broadcast (write own -> read full vector) gets ~1 iteration of
// latency cover, so the ~120-cyc LDS round-trip stays off the critical path.
__global__ void __launch_bounds__(64) rnn_kernel(
    const float* __restrict__ x,    const float* __restrict__ hs,
    const float* __restrict__ Wih0, const float* __restrict__ Whh0,
    const float* __restrict__ bih0, const float* __restrict__ bhh0,
    const float* __restrict__ Wih1, const float* __restrict__ Whh1,
    const float* __restrict__ bih1, const float* __restrict__ bhh1,
    const float* __restrict__ Wout, const float* __restrict__ boutp,
    float* __restrict__ out)
{
    const int tid  = threadIdx.x;
    const int lane = tid & 15;          // hidden unit slot
    const int grp  = tid >> 4;          // row within wave
    const int row  = blockIdx.x * 4 + grp;

    // 48-float stride => group bases 16 banks apart => <=2-way aliasing (free)
    __shared__ float lds[4 * 48];
    float* hbuf = &lds[grp * 48];

    float whh0[HID], wih1[HID], whh1[HID], wout[HID];
    float wih0i, b0c, b1c;
    if (lane < HID) {
        #pragma unroll
        for (int j = 0; j < HID; ++j) {
            whh0[j] = Whh0[lane * HID + j];
            wih1[j] = Wih1[lane * HID + j];
            whh1[j] = Whh1[lane * HID + j];
        }
        wih0i = Wih0[lane];
        b0c   = bih0[lane] + bhh0[lane];
        b1c   = bih1[lane] + bhh1[lane];
    } else {
        #pragma unroll
        for (int j = 0; j < HID; ++j) { whh0[j] = 0.f; wih1[j] = 0.f; whh1[j] = 0.f; }
        wih0i = 0.f; b0c = 0.f; b1c = 0.f;
    }
    #pragma unroll
    for (int j = 0; j < HID; ++j) wout[j] = Wout[j];
    const float bo = boutp[0];

    // broadcast state vectors (every lane holds full h0/h1)
    float H0B[HID], H1B[HID];
    #pragma unroll
    for (int j = 0; j < HID; ++j) {
        H0B[j] = hs[row * HID + j];
        H1B[j] = hs[BB * HID + row * HID + j];
    }

    const float* xrow = x   + (size_t)row * TT;
    float*       orow = out + (size_t)row * TT;

    float4 n0, n1; float2 n2;   // in-flight h0 broadcast
    float4 m0, m1; float2 m2;   // in-flight h1 broadcast
    float h0own = 0.f, h1own = 0.f;
    float st0 = 0.f, st1 = 0.f, st2 = 0.f, st3 = 0.f;  // out staging by t&3

#define STEP_L0(XW) do {                                                \
    float _a = fmaf((XW), wih0i, b0c), _b = 0.f;                        \
    _Pragma("unroll")                                                   \
    for (int j = 0; j < HID; j += 2) {                                  \
        _a = fmaf(whh0[j],   H0B[j],   _a);                             \
        _b = fmaf(whh0[j+1], H0B[j+1], _b);                             \
    }                                                                   \
    h0own = fast_tanh(_a + _b);                                         \
    hbuf[lane] = h0own;                                                 \
    __builtin_amdgcn_wave_barrier();                                    \
    n0 = *(const float4*)&hbuf[0];                                      \
    n1 = *(const float4*)&hbuf[4];                                      \
    n2 = *(const float2*)&hbuf[8];                                      \
    __builtin_amdgcn_wave_barrier();                                    \
} while (0)

#define STEP_L1() do {                                                  \
    float _a = b1c, _b = 0.f, _c = 0.f, _d = 0.f;                       \
    _Pragma("unroll")                                                   \
    for (int j = 0; j < HID; j += 2) {                                  \
        _a = fmaf(wih1[j],   H0B[j],   _a);                             \
        _b = fmaf(wih1[j+1], H0B[j+1], _b);                             \
        _c = fmaf(whh1[j],   H1B[j],   _c);                             \
        _d = fmaf(whh1[j+1], H1B[j+1], _d);                             \
    }                                                                   \
    h1own = fast_tanh((_a + _b) + (_c + _d));                           \
    hbuf[16 + lane] = h1own;                                            \
    __builtin_amdgcn_wave_barrier();                                    \
    m0 = *(const float4*)&hbuf[16];                                     \
    m1 = *(const float4*)&hbuf[20];                                     \
    m2 = *(const float2*)&hbuf[24];                                     \
    __builtin_amdgcn_wave_barrier();                                    \
} while (0)

#define OUTDOT(DST) do {                                                \
    float _a = 0.f, _b = 0.f;                                           \
    _Pragma("unroll")                                                   \
    for (int j = 0; j < HID; j += 2) {                                  \
        _a = fmaf(wout[j],   H1B[j],   _a);                             \
        _b = fmaf(wout[j+1], H1B[j+1], _b);                             \
    }                                                                   \
    DST = (_a + _b) + bo;                                               \
} while (0)

#define COMMIT_H0() do {                                                \
    H0B[0]=n0.x; H0B[1]=n0.y; H0B[2]=n0.z; H0B[3]=n0.w;                 \
    H0B[4]=n1.x; H0B[5]=n1.y; H0B[6]=n1.z; H0B[7]=n1.w;                 \
    H0B[8]=n2.x; H0B[9]=n2.y;                                           \
} while (0)

#define COMMIT_H1() do {                                                \
    H1B[0]=m0.x; H1B[1]=m0.y; H1B[2]=m0.z; H1B[3]=m0.w;                 \
    H1B[4]=m1.x; H1B[5]=m1.y; H1B[6]=m1.z; H1B[7]=m1.w;                 \
    H1B[8]=m2.x; H1B[9]=m2.y;                                           \
} while (0)

    // -------- prologue: i = 0..3 --------
    float4 xcur = *(const float4*)(xrow);        // x[0..3]
    float4 xnxt = *(const float4*)(xrow + 4);    // x[4..7]

    STEP_L0(xcur.x);                                   // i=0
    COMMIT_H0();
    STEP_L0(xcur.y); STEP_L1();                        // i=1, layer1(0)
    COMMIT_H0(); COMMIT_H1();
    STEP_L0(xcur.z); STEP_L1(); OUTDOT(st0);           // i=2, out(0)
    COMMIT_H0(); COMMIT_H1();
    STEP_L0(xcur.w); STEP_L1(); OUTDOT(st1);           // i=3, out(1)
    COMMIT_H0(); COMMIT_H1();

    // -------- main: b = 1..511, i = 4b+k --------
    for (int b = 1; b < TT / 4; ++b) {
        const int pf = (b < TT / 4 - 1) ? (b + 1) * 4 : (TT / 4 - 1) * 4;
        float4 xload = *(const float4*)(xrow + pf);    // prefetch next block

        STEP_L0(xnxt.x); STEP_L1(); OUTDOT(st2);       // k=0: out(4b-2)
        COMMIT_H0(); COMMIT_H1();
        STEP_L0(xnxt.y); STEP_L1(); OUTDOT(st3);       // k=1: out(4b-1)
        COMMIT_H0(); COMMIT_H1();
        if (lane == 0) {
            *(float4*)(orow + 4 * b - 4) = make_float4(st0, st1, st2, st3);
        }
        STEP_L0(xnxt.z); STEP_L1(); OUTDOT(st0);       // k=2: out(4b)
        COMMIT_H0(); COMMIT_H1();
        STEP_L0(xnxt.w); STEP_L1(); OUTDOT(st1);       // k=3: out(4b+1)
        COMMIT_H0(); COMMIT_H1();

        xnxt = xload;
    }

    // -------- epilogue --------
    // After loop: H0B=h0(2047), H1B=h1(2046), h0own=h0(2047) own unit.
    OUTDOT(st2);                // out(2046) = Wout . h1(2046)
    STEP_L1();                  // layer1(2047): h0(2047), h1(2046) -> h1(2047)
    COMMIT_H1();                // H1B = h1(2047)
    OUTDOT(st3);                // out(2047)
    if (lane == 0) {
        *(float4*)(orow + TT - 4) = make_float4(st0, st1, st2, st3);
    }

    // final hidden state: [2, B, H] appended after B*T outputs
    if (lane < HID) {
        out[(size_t)BB * TT + (size_t)row * HID + lane]                    = h0own;
        out[(size_t)BB * TT + (size_t)BB * HID + (size_t)row * HID + lane] = h1own;
    }

#undef STEP_L0
#undef STEP_L1
#undef OUTDOT
#undef COMMIT_H0
#undef COMMIT_H1
}

extern "C" void kernel_launch(void* const* d_in, const int* in_sizes, int n_in,
                              void* d_out, int out_size, void* d_ws, size_t ws_size,
                              hipStream_t stream) {
    const float* x    = (const float*)d_in[0];
    const float* hs   = (const float*)d_in[1];
    const float* Wih0 = (const float*)d_in[2];
    const float* Whh0 = (const float*)d_in[3];
    const float* bih0 = (const float*)d_in[4];
    const float* bhh0 = (const float*)d_in[5];
    const float* Wih1 = (const float*)d_in[6];
    const float* Whh1 = (const float*)d_in[7];
    const float* bih1 = (const float*)d_in[8];
    const float* bhh1 = (const float*)d_in[9];
    const float* Wout = (const float*)d_in[10];
    const float* bout = (const float*)d_in[11];
    float* out = (float*)d_out;

    dim3 grid(BB / 4), block(64);
    hipLaunchKernelGGL(rnn_kernel, grid, block, 0, stream,
        x, hs, Wih0, Whh0, bih0, bhh0, Wih1, Whh1, bih1, bhh1, Wout, bout, out);
}